// Round 1
// baseline (111.102 us; speedup 1.0000x reference)
//
#include <hip/hip_runtime.h>

// CARAFE: features [4,256,64,64] f32, masks [4,25,128,128] f32 -> out [4,256,128,128] f32
// out[n,c,2h+p,2w+q] = sum_{i,j} masks[n,i*5+j,2h+p,2w+q] * feat[n,c,h+i-2,w+j-2]

#define CN 4
#define CC 256
#define CH 64
#define CW 64
#define CK 5
#define OH 128
#define OW 128

constexpr int TILE = 16;              // low-res tile (16x16 positions per block)
constexpr int SROWS = TILE + 4;       // 20 staged rows
constexpr int SCOLS = TILE + 4;       // 20 staged cols
constexpr int LSTR  = 24;             // LDS row stride: rows hit banks {0,24,16,8} mod 32 -> pure 2-way (free)
constexpr int LBUF  = SROWS * LSTR;   // 480 floats per buffer
constexpr int CH_PER_BLOCK = 32;      // 8 channel chunks -> 512 blocks total

__global__ __launch_bounds__(256, 2)
void carafe_kernel(const float* __restrict__ feat,
                   const float* __restrict__ masks,
                   float* __restrict__ out)
{
    __shared__ float lds[2 * LBUF];

    const int tid  = threadIdx.x;
    const int wloc = tid & 15;
    const int hloc = tid >> 4;

    const int w0 = blockIdx.x * TILE;
    const int h0 = blockIdx.y * TILE;
    const int z  = blockIdx.z;          // n*8 + chunk
    const int n  = z >> 3;
    const int c0 = (z & 7) * CH_PER_BLOCK;

    // ---- staging element assignment (channel-independent) ----
    // 400 staged elements; thread handles e0=tid and e1=tid+256 (if <400)
    const int r0 = tid / SCOLS, q0 = tid % SCOLS;
    const int gr0 = h0 - 2 + r0, gc0 = w0 - 2 + q0;
    const bool val0 = (gr0 >= 0) & (gr0 < CH) & (gc0 >= 0) & (gc0 < CW);
    const int off0 = val0 ? (gr0 * CW + gc0) : 0;
    const int l0   = r0 * LSTR + q0;

    const int e1 = tid + 256;
    const bool has1 = e1 < SROWS * SCOLS;          // tid < 144
    const int r1 = e1 / SCOLS, q1 = e1 % SCOLS;
    const int gr1 = h0 - 2 + r1, gc1 = w0 - 2 + q1;
    const bool val1 = has1 & (gr1 >= 0) & (gr1 < CH) & (gc1 >= 0) & (gc1 < CW);
    const int off1 = val1 ? (gr1 * CW + gc1) : 0;
    const int l1   = r1 * LSTR + q1;

    const float* fbase = feat + (size_t)(n * CC + c0) * (CH * CW);

    // ---- load this thread's 100 mask values into registers ----
    const int oh0 = 2 * (h0 + hloc);
    const int ow0 = 2 * (w0 + wloc);
    const float* mp = masks + (((size_t)n * (CK * CK)) * OH + oh0) * OW + ow0;
    float2 m0[25], m1[25];
#pragma unroll
    for (int t = 0; t < 25; ++t) {
        m0[t] = *(const float2*)(mp + (size_t)t * (OH * OW));
        m1[t] = *(const float2*)(mp + (size_t)t * (OH * OW) + OW);
    }

    // ---- software pipeline: 2-channel-deep global prefetch, double-buffered LDS ----
    float pa, pb;
    // channel 0 -> buf0
    pa = val0 ? fbase[off0] : 0.0f;
    pb = val1 ? fbase[(size_t)CH * CW + 0 + off1] : 0.0f;  // placeholder, fixed below
    // (re-load properly: channel 0 for both elements)
    pa = val0 ? fbase[off0] : 0.0f;
    pb = val1 ? fbase[off1] : 0.0f;
    lds[l0] = pa;
    if (has1) lds[l1] = pb;
    // channel 1 into prefetch regs
    pa = val0 ? fbase[1 * (CH * CW) + off0] : 0.0f;
    pb = val1 ? fbase[1 * (CH * CW) + off1] : 0.0f;

    float* obase = out + (((size_t)(n * CC + c0) * OH + oh0) * OW + ow0);

    for (int ci = 0; ci < CH_PER_BLOCK; ++ci) {
        __syncthreads();   // buf[ci&1] filled; all waves done reading buf[(ci+1)&1]

        if (ci + 1 < CH_PER_BLOCK) {
            float* dst = &lds[((ci + 1) & 1) * LBUF];
            dst[l0] = pa;
            if (has1) dst[l1] = pb;
        }
        if (ci + 2 < CH_PER_BLOCK) {
            const float* fc = fbase + (size_t)(ci + 2) * (CH * CW);
            pa = val0 ? fc[off0] : 0.0f;
            pb = val1 ? fc[off1] : 0.0f;
        }

        // ---- compute 2x2 outputs for this (h,w) across channel ci ----
        const float* lb = &lds[(ci & 1) * LBUF + hloc * LSTR + wloc];
        float a00 = 0.f, a01 = 0.f, a10 = 0.f, a11 = 0.f;
#pragma unroll
        for (int i = 0; i < CK; ++i) {
#pragma unroll
            for (int j = 0; j < CK; ++j) {
                const int t = i * CK + j;
                const float f = lb[i * LSTR + j];
                a00 += m0[t].x * f;
                a01 += m0[t].y * f;
                a10 += m1[t].x * f;
                a11 += m1[t].y * f;
            }
        }

        float* op = obase + (size_t)ci * (OH * OW);
        *(float2*)op          = make_float2(a00, a01);
        *(float2*)(op + OW)   = make_float2(a10, a11);
    }
}

extern "C" void kernel_launch(void* const* d_in, const int* in_sizes, int n_in,
                              void* d_out, int out_size, void* d_ws, size_t ws_size,
                              hipStream_t stream) {
    const float* feat  = (const float*)d_in[0];
    const float* masks = (const float*)d_in[1];
    float* out = (float*)d_out;

    dim3 grid(CW / TILE, CH / TILE, CN * (CC / CH_PER_BLOCK));  // 4 x 4 x 32 = 512 blocks
    dim3 block(256);
    hipLaunchKernelGGL(carafe_kernel, grid, block, 0, stream, feat, masks, out);
}

// Round 3
// 105.492 us; speedup vs baseline: 1.0532x; 1.0532x over previous
//
#include <hip/hip_runtime.h>

// CARAFE: features [4,256,64,64] f32, masks [4,25,128,128] f32 -> out [4,256,128,128] f32
// out[n,c,2h+p,2w+q] = sum_{i,j} masks[n,i*5+j,2h+p,2w+q] * feat[n,c,h+i-2,w+j-2]

#define CN 4
#define CC 256
#define CH 64
#define CW 64
#define CK 5
#define OH 128
#define OW 128

typedef float f32x2 __attribute__((ext_vector_type(2)));   // native vector for nontemporal stores

constexpr int TILE  = 16;             // 16x16 low-res positions per block
constexpr int SROWS = TILE + 4;       // 20 staged rows
constexpr int LSTR  = 24;             // row stride in float2 units
constexpr int LBUF  = SROWS * LSTR;   // 480 float2 per channel-pair
constexpr int CPB   = 4;              // channels per stage (= 2 float2-pairs)
constexpr int PPS   = CPB / 2;        // channel-pairs per stage
constexpr int CH_PER_BLOCK = 32;
constexpr int NSTG  = CH_PER_BLOCK / CPB;   // 8 stages -> 8 barriers (was 32)

__global__ __launch_bounds__(256, 2)
void carafe_kernel(const float* __restrict__ feat,
                   const float* __restrict__ masks,
                   float* __restrict__ out)
{
    // 2 stage-buffers x 2 pairs x 480 float2 = 15360 B
    __shared__ float2 lds[2 * PPS * LBUF];

    const int tid  = threadIdx.x;
    const int wloc = tid & 15;
    const int hloc = tid >> 4;

    const int w0 = blockIdx.x * TILE;
    const int h0 = blockIdx.y * TILE;
    const int z  = blockIdx.z;          // n*8 + chunk
    const int n  = z >> 3;
    const int c0 = (z & 7) * CH_PER_BLOCK;

    // ---- staging assignment: thread t<200 owns float2-pair (row r, cols q,q+1) ----
    const int r  = tid / 10;            // 0..19 (for tid<200)
    const int pc = tid % 10;            // 0..9
    const int q  = 2 * pc;
    const int gr = h0 - 2 + r;
    const int gc = w0 - 2 + q;          // always even -> float2-aligned
    const bool sv = (tid < 200) & (gr >= 0) & (gr < CH) & (gc >= 0) & (gc <= CW - 2);
    const int goff = sv ? (gr * CW + gc) : 0;
    const int l    = r * LSTR + q;      // LDS f2 slots l, l+1

    const float* fbase = feat + (size_t)(n * CC + c0) * (CH * CW);

    // ---- per-thread mask registers: 25 taps x 2x2 output pixels ----
    const int oh0 = 2 * (h0 + hloc);
    const int ow0 = 2 * (w0 + wloc);
    const float* mp = masks + (((size_t)n * (CK * CK)) * OH + oh0) * OW + ow0;
    float2 m0[25], m1[25];
#pragma unroll
    for (int t = 0; t < 25; ++t) {
        m0[t] = *(const float2*)(mp + (size_t)t * (OH * OW));
        m1[t] = *(const float2*)(mp + (size_t)t * (OH * OW) + OW);
    }

    // ---- stage prefetch registers: pa[p] = ch(2p) f2, pb[p] = ch(2p+1) f2 ----
    float2 pa[PPS], pb[PPS];

    auto loadStage = [&](int s) {
#pragma unroll
        for (int p = 0; p < PPS; ++p) {
            const float* f0 = fbase + (size_t)(s * CPB + 2 * p) * (CH * CW);
            pa[p] = sv ? *(const float2*)(f0 + goff) : make_float2(0.f, 0.f);
            pb[p] = sv ? *(const float2*)(f0 + CH * CW + goff) : make_float2(0.f, 0.f);
        }
    };
    auto writeStage = [&](int buf) {
        if (tid < 200) {
            float2* dst = &lds[buf * (PPS * LBUF)];
#pragma unroll
            for (int p = 0; p < PPS; ++p) {
                // interleave channel pair: lds[...].x = ch(2p), .y = ch(2p+1)
                dst[p * LBUF + l]     = make_float2(pa[p].x, pb[p].x);
                dst[p * LBUF + l + 1] = make_float2(pa[p].y, pb[p].y);
            }
        }
    };

    // ---- prologue: stage0 -> buf0, stage1 -> regs ----
    loadStage(0);
    writeStage(0);
    loadStage(1);

    float* obase = out + (((size_t)(n * CC + c0) * OH + oh0) * OW + ow0);

    for (int s = 0; s < NSTG; ++s) {
        __syncthreads();                 // buf[s&1] ready; buf[(s+1)&1] free to overwrite

        if (s + 1 < NSTG) writeStage((s + 1) & 1);   // regs hold stage s+1
        if (s + 2 < NSTG) loadStage(s + 2);          // full stage of latency slack

        const float2* sb = &lds[(s & 1) * (PPS * LBUF)];
#pragma unroll
        for (int p = 0; p < PPS; ++p) {
            const float2* lb = sb + p * LBUF + hloc * LSTR + wloc;
            float a00 = 0.f, a01 = 0.f, a10 = 0.f, a11 = 0.f;   // channel 2p
            float b00 = 0.f, b01 = 0.f, b10 = 0.f, b11 = 0.f;   // channel 2p+1
#pragma unroll
            for (int i = 0; i < CK; ++i) {
#pragma unroll
                for (int j = 0; j < CK; ++j) {
                    const int t = i * CK + j;
                    const float2 f = lb[i * LSTR + j];   // ds_read_b64, always 8B-aligned
                    a00 += m0[t].x * f.x; a01 += m0[t].y * f.x;
                    a10 += m1[t].x * f.x; a11 += m1[t].y * f.x;
                    b00 += m0[t].x * f.y; b01 += m0[t].y * f.y;
                    b10 += m1[t].x * f.y; b11 += m1[t].y * f.y;
                }
            }
            float* op0 = obase + (size_t)(s * CPB + 2 * p) * (OH * OW);
            float* op1 = op0 + (OH * OW);
            __builtin_nontemporal_store((f32x2){a00, a01}, (f32x2*)op0);
            __builtin_nontemporal_store((f32x2){a10, a11}, (f32x2*)(op0 + OW));
            __builtin_nontemporal_store((f32x2){b00, b01}, (f32x2*)op1);
            __builtin_nontemporal_store((f32x2){b10, b11}, (f32x2*)(op1 + OW));
        }
    }
}

extern "C" void kernel_launch(void* const* d_in, const int* in_sizes, int n_in,
                              void* d_out, int out_size, void* d_ws, size_t ws_size,
                              hipStream_t stream) {
    const float* feat  = (const float*)d_in[0];
    const float* masks = (const float*)d_in[1];
    float* out = (float*)d_out;

    dim3 grid(CW / TILE, CH / TILE, CN * (CC / CH_PER_BLOCK));  // 4 x 4 x 32 = 512 blocks
    dim3 block(256);
    hipLaunchKernelGGL(carafe_kernel, grid, block, 0, stream, feat, masks, out);
}

// Round 4
// 102.926 us; speedup vs baseline: 1.0794x; 1.0249x over previous
//
#include <hip/hip_runtime.h>

// CARAFE: features [4,256,64,64] f32, masks [4,25,128,128] f32 -> out [4,256,128,128] f32
// out[n,c,2h+p,2w+q] = sum_{i,j} masks[n,i*5+j,2h+p,2w+q] * feat[n,c,h+i-2,w+j-2]
//
// Tap-outer structure: accumulators live in registers (32 f32/thread), masks are
// streamed 2xfloat2 per tap (prefetched one tap ahead), features staged once per
// block in LDS as channel-pair-interleaved float2 planes -> ds_read_b64 serves
// 2 channels x (shared by the 2x2 output quad) per instruction.

#define CN 4
#define CC 256
#define CH 64
#define CW 64
#define CK 5
#define OH 128
#define OW 128

typedef float f32x2 __attribute__((ext_vector_type(2)));

constexpr int TILE  = 16;             // 16x16 low-res positions per block
constexpr int SROWS = TILE + 4;       // 20 staged rows
constexpr int LSTR  = 24;             // row stride in float2 units
constexpr int LBUF  = SROWS * LSTR;   // 480 float2 per channel-pair plane
constexpr int CPB   = 8;              // channels per block (whole chunk, 1 barrier)
constexpr int PPS   = CPB / 2;        // 4 pair planes

__global__ __launch_bounds__(256, 4)
void carafe_kernel(const float* __restrict__ feat,
                   const float* __restrict__ masks,
                   float* __restrict__ out)
{
    __shared__ float2 lds[PPS * LBUF];   // 15360 B, single-buffered

    const int tid  = threadIdx.x;
    const int wloc = tid & 15;
    const int hloc = tid >> 4;

    const int w0 = blockIdx.x * TILE;
    const int h0 = blockIdx.y * TILE;
    const int z  = blockIdx.z;           // n*32 + chunk
    const int n  = z >> 5;
    const int c0 = (z & 31) * CPB;

    // ---- staging: thread t<200 owns float2-pair (row r, cols q,q+1) of the 20x20 halo ----
    const int r  = tid / 10;
    const int q  = 2 * (tid % 10);
    const int gr = h0 - 2 + r;
    const int gc = w0 - 2 + q;           // even -> float2-aligned
    const bool sv = (tid < 200) & (gr >= 0) & (gr < CH) & (gc >= 0) & (gc <= CW - 2);
    const int goff = sv ? (gr * CW + gc) : 0;
    const int l    = r * LSTR + q;

    const float* fbase = feat + (size_t)(n * CC + c0) * (CH * CW);

    // issue all staging loads (8 channels = 4 pairs), then interleave into LDS
    float2 pa[PPS], pb[PPS];
#pragma unroll
    for (int p = 0; p < PPS; ++p) {
        const float* f0 = fbase + (size_t)(2 * p) * (CH * CW);
        pa[p] = sv ? *(const float2*)(f0 + goff) : make_float2(0.f, 0.f);
        pb[p] = sv ? *(const float2*)(f0 + CH * CW + goff) : make_float2(0.f, 0.f);
    }
    if (tid < 200) {
#pragma unroll
        for (int p = 0; p < PPS; ++p) {
            lds[p * LBUF + l]     = make_float2(pa[p].x, pb[p].x);
            lds[p * LBUF + l + 1] = make_float2(pa[p].y, pb[p].y);
        }
    }

    // ---- mask stream setup: this thread's 2x2 output pixels ----
    const int oh0 = 2 * (h0 + hloc);
    const int ow0 = 2 * (w0 + wloc);
    const float* mp = masks + (((size_t)n * (CK * CK)) * OH + oh0) * OW + ow0;

    float2 cm0 = *(const float2*)(mp);        // tap 0, output row p=0
    float2 cm1 = *(const float2*)(mp + OW);   // tap 0, output row p=1

    __syncthreads();

    // accumulators: a0[c] = out row oh0 (ow0, ow0+1); a1[c] = row oh0+1
    float2 a0[CPB], a1[CPB];
#pragma unroll
    for (int c = 0; c < CPB; ++c) {
        a0[c] = make_float2(0.f, 0.f);
        a1[c] = make_float2(0.f, 0.f);
    }

    const float2* lb = &lds[hloc * LSTR + wloc];

#pragma unroll
    for (int t = 0; t < CK * CK; ++t) {
        const int i = t / CK, j = t % CK;

        float2 nm0 = cm0, nm1 = cm1;
        if (t + 1 < CK * CK) {           // prefetch next tap's masks (L2/L3 hit)
            nm0 = *(const float2*)(mp + (size_t)(t + 1) * (OH * OW));
            nm1 = *(const float2*)(mp + (size_t)(t + 1) * (OH * OW) + OW);
        }

        float2 f[PPS];
#pragma unroll
        for (int p = 0; p < PPS; ++p)
            f[p] = lb[p * LBUF + i * LSTR + j];   // ds_read_b64, 2 channels

#pragma unroll
        for (int p = 0; p < PPS; ++p) {
            a0[2 * p].x     += cm0.x * f[p].x;  a0[2 * p].y     += cm0.y * f[p].x;
            a1[2 * p].x     += cm1.x * f[p].x;  a1[2 * p].y     += cm1.y * f[p].x;
            a0[2 * p + 1].x += cm0.x * f[p].y;  a0[2 * p + 1].y += cm0.y * f[p].y;
            a1[2 * p + 1].x += cm1.x * f[p].y;  a1[2 * p + 1].y += cm1.y * f[p].y;
        }
        cm0 = nm0; cm1 = nm1;
    }

    // ---- epilogue: coalesced nontemporal float2 stores ----
    float* obase = out + (((size_t)(n * CC + c0) * OH + oh0) * OW + ow0);
#pragma unroll
    for (int c = 0; c < CPB; ++c) {
        float* op = obase + (size_t)c * (OH * OW);
        __builtin_nontemporal_store((f32x2){a0[c].x, a0[c].y}, (f32x2*)op);
        __builtin_nontemporal_store((f32x2){a1[c].x, a1[c].y}, (f32x2*)(op + OW));
    }
}

extern "C" void kernel_launch(void* const* d_in, const int* in_sizes, int n_in,
                              void* d_out, int out_size, void* d_ws, size_t ws_size,
                              hipStream_t stream) {
    const float* feat  = (const float*)d_in[0];
    const float* masks = (const float*)d_in[1];
    float* out = (float*)d_out;

    dim3 grid(CW / TILE, CH / TILE, CN * (CC / CPB));  // 4 x 4 x 128 = 2048 blocks
    dim3 block(256);
    hipLaunchKernelGGL(carafe_kernel, grid, block, 0, stream, feat, masks, out);
}

// Round 5
// 102.049 us; speedup vs baseline: 1.0887x; 1.0086x over previous
//
#include <hip/hip_runtime.h>

// CARAFE: features [4,256,64,64] f32, masks [4,25,128,128] f32 -> out [4,256,128,128] f32
// out[n,c,2h+p,2w+q] = sum_{i,j} masks[n,i*5+j,2h+p,2w+q] * feat[n,c,h+i-2,w+j-2]
//
// Tap-outer, accumulator-resident structure with an EXPLICIT 8-deep mask
// prefetch queue: mask loads for tap t+8 issue ~550 cycles before use,
// covering L2/L3 latency even at moderate wave counts. Features staged once
// per block in LDS as channel-pair float2 planes (ds_read_b64 serves 2
// channels; value reused by 8 FMAs).

#define CN 4
#define CC 256
#define CH 64
#define CW 64
#define CK 5
#define OH 128
#define OW 128

typedef float f32x2 __attribute__((ext_vector_type(2)));
typedef float f32x4 __attribute__((ext_vector_type(4)));

constexpr int TILE  = 16;             // 16x16 low-res positions per block
constexpr int SROWS = TILE + 4;       // 20 staged rows
constexpr int LSTR  = 24;             // row stride in float2 units
constexpr int LBUF  = SROWS * LSTR;   // 480 float2 per channel-pair plane
constexpr int CPB   = 8;              // channels per block, single barrier
constexpr int PPS   = CPB / 2;        // 4 pair planes
constexpr int NTAP  = CK * CK;        // 25
constexpr int MQ    = 8;              // mask prefetch depth (taps): 8*~70cyc > L3 latency

__global__ __launch_bounds__(256, 4)
void carafe_kernel(const float* __restrict__ feat,
                   const float* __restrict__ masks,
                   float* __restrict__ out)
{
    __shared__ float2 lds[PPS * LBUF];   // 15360 B

    const int tid  = threadIdx.x;
    const int wloc = tid & 15;
    const int hloc = tid >> 4;

    const int w0 = blockIdx.x * TILE;
    const int h0 = blockIdx.y * TILE;
    const int z  = blockIdx.z;           // n*32 + chunk
    const int n  = z >> 5;
    const int c0 = (z & 31) * CPB;

    // ---- mask queue: issue first MQ taps BEFORE staging so they overlap ----
    const int oh0 = 2 * (h0 + hloc);
    const int ow0 = 2 * (w0 + wloc);
    const float* mp = masks + (((size_t)n * NTAP) * OH + oh0) * OW + ow0;

    float2 q0[MQ], q1[MQ];               // 32 VGPRs of in-flight masks
#pragma unroll
    for (int t = 0; t < MQ; ++t) {
        q0[t] = *(const float2*)(mp + (size_t)t * (OH * OW));
        q1[t] = *(const float2*)(mp + (size_t)t * (OH * OW) + OW);
    }

    // ---- feature staging: thread t<200 owns float2-pair (row r, cols q,q+1) ----
    const int r  = tid / 10;
    const int qq = 2 * (tid % 10);
    const int gr = h0 - 2 + r;
    const int gc = w0 - 2 + qq;          // even -> float2-aligned
    const bool sv = (tid < 200) & (gr >= 0) & (gr < CH) & (gc >= 0) & (gc <= CW - 2);
    const int goff = sv ? (gr * CW + gc) : 0;
    const int l    = r * LSTR + qq;      // even -> 16B-aligned LDS slot

    const float* fbase = feat + (size_t)(n * CC + c0) * (CH * CW);

    float2 pa[PPS], pb[PPS];
#pragma unroll
    for (int p = 0; p < PPS; ++p) {
        const float* f0 = fbase + (size_t)(2 * p) * (CH * CW);
        pa[p] = sv ? *(const float2*)(f0 + goff) : make_float2(0.f, 0.f);
        pb[p] = sv ? *(const float2*)(f0 + CH * CW + goff) : make_float2(0.f, 0.f);
    }
    if (tid < 200) {
#pragma unroll
        for (int p = 0; p < PPS; ++p) {
            // interleaved channel pair, one 16B ds_write_b128
            *(f32x4*)&lds[p * LBUF + l] = (f32x4){pa[p].x, pb[p].x, pa[p].y, pb[p].y};
        }
    }

    __syncthreads();

    // ---- accumulators: 2x2 output pixels x 8 channels = 32 floats ----
    float2 a0[CPB], a1[CPB];
#pragma unroll
    for (int c = 0; c < CPB; ++c) {
        a0[c] = make_float2(0.f, 0.f);
        a1[c] = make_float2(0.f, 0.f);
    }

    const float2* lb = &lds[hloc * LSTR + wloc];

#pragma unroll
    for (int t = 0; t < NTAP; ++t) {
        const int i = t / CK, j = t % CK;
        const int slot = t % MQ;                 // static after full unroll
        const float2 cm0 = q0[slot];
        const float2 cm1 = q1[slot];

        if (t + MQ < NTAP) {                     // refill queue 8 taps ahead
            q0[slot] = *(const float2*)(mp + (size_t)(t + MQ) * (OH * OW));
            q1[slot] = *(const float2*)(mp + (size_t)(t + MQ) * (OH * OW) + OW);
        }

        float2 f[PPS];
#pragma unroll
        for (int p = 0; p < PPS; ++p)
            f[p] = lb[p * LBUF + i * LSTR + j];  // ds_read_b64, 2 channels

#pragma unroll
        for (int p = 0; p < PPS; ++p) {
            a0[2 * p].x     += cm0.x * f[p].x;  a0[2 * p].y     += cm0.y * f[p].x;
            a1[2 * p].x     += cm1.x * f[p].x;  a1[2 * p].y     += cm1.y * f[p].x;
            a0[2 * p + 1].x += cm0.x * f[p].y;  a0[2 * p + 1].y += cm0.y * f[p].y;
            a1[2 * p + 1].x += cm1.x * f[p].y;  a1[2 * p + 1].y += cm1.y * f[p].y;
        }
    }

    // ---- epilogue: coalesced nontemporal float2 stores ----
    float* obase = out + (((size_t)(n * CC + c0) * OH + oh0) * OW + ow0);
#pragma unroll
    for (int c = 0; c < CPB; ++c) {
        float* op = obase + (size_t)c * (OH * OW);
        __builtin_nontemporal_store((f32x2){a0[c].x, a0[c].y}, (f32x2*)op);
        __builtin_nontemporal_store((f32x2){a1[c].x, a1[c].y}, (f32x2*)(op + OW));
    }
}

extern "C" void kernel_launch(void* const* d_in, const int* in_sizes, int n_in,
                              void* d_out, int out_size, void* d_ws, size_t ws_size,
                              hipStream_t stream) {
    const float* feat  = (const float*)d_in[0];
    const float* masks = (const float*)d_in[1];
    float* out = (float*)d_out;

    dim3 grid(CW / TILE, CH / TILE, CN * (CC / CPB));  // 4 x 4 x 128 = 2048 blocks
    dim3 block(256);
    hipLaunchKernelGGL(carafe_kernel, grid, block, 0, stream, feat, masks, out);
}